// Round 3
// baseline (1635.703 us; speedup 1.0000x reference)
//
#include <hip/hip_runtime.h>
#include <hip/hip_fp16.h>

// GPTQ int4 dequant + GEMM, fused.  R3: packed-fp16 magic-number dequant.
//
//   x        [4,2048,4096] fp32  -> A [M=8192][K=4096], cast fp16 RTE (== ref)
//   qweight  [512,11008] int32   -> W[k][n]: nibble j of qweight[k/8][n], k=8*(k/8)+j
//   qzeros   [32,1376]  int32    -> z[g][n]: nibble (n%8) of qzeros[g][n/8]
//   scales   [32,11008]          -> harness materializes fp16 inputs as FP32 buffers
//   dequant  fp16((w - z)*s): via 0x6400|nib trick -> (1024+nib) exact fp16;
//            pk_sub (exact) + pk_mul (single RTE of exact product) == ref's
//            fp32-math-then-RTE bit for bit.
//   out      [M][N=11008] fp32, fp32 MFMA accumulation
//
// k-permutation: the shift trick yields nibble pairs (j, j+4) -> storing them
// consecutively puts each 8-k octet in order s = [0,4,1,5,2,6,3,7]. A's LDS
// layout applies the SAME permutation (MFMA sums over register position, so a
// consistent intra-octet permutation is correct; octets never cross a
// 128-wide scale group).
//
// Structure: 128x128 tile, BK=64, 4 waves 2x2, wave tile 64x64 = 4x4 frags of
// mfma_f32_16x16x32_f16. LDS As[m][k], Bs[n][k], LDK=72 halves (144 B row
// stride -> negligible conflicts, verified R2: 9e7 cycles = 0.01%).

#define M_TOT 8192
#define N_TOT 11008
#define K_TOT 4096
#define GROUPS 32

#define BM 128
#define BN 128
#define BK 64
#define LDK 72  // padded K stride in halves (144 B = 9*16B, keeps b128 alignment)

typedef _Float16 half8 __attribute__((ext_vector_type(8)));
typedef _Float16 half2v __attribute__((ext_vector_type(2)));
typedef float float4v __attribute__((ext_vector_type(4)));

__global__ __launch_bounds__(256) void gptq_fused_gemm(
    const float* __restrict__ x,
    const unsigned* __restrict__ qw,
    const unsigned* __restrict__ qz,
    const float* __restrict__ sc,   // fp32 buffer (harness upcasts fp16 inputs)
    float* __restrict__ out)
{
    __shared__ _Float16 As[BM * LDK];
    __shared__ _Float16 Bs[BN * LDK];

    const int tid = threadIdx.x;
    const int bn = blockIdx.x;            // 0..85  (N/128)
    const int bm = blockIdx.y;            // 0..63  (M/128)
    const int m0 = bm * BM;
    const int n0 = bn * BN;

    const int wave = tid >> 6;
    const int lane = tid & 63;
    const int wr = wave >> 1;             // wave row (m), 0..1
    const int wc = wave & 1;              // wave col (n), 0..1
    const int l16 = lane & 15;
    const int quad = lane >> 4;

    // A staging: thread owns 8 consecutive k (one octet) of rows a_r0 + 32*i
    const int a_oct = tid & 7;            // k-octet 0..7  (k = 8*a_oct .. +8)
    const int a_r0  = tid >> 3;           // row base 0..31
    // B staging: thread -> column b_n, qweight rows b_rr + 2*i
    const int b_n  = tid & 127;
    const int b_rr = tid >> 7;
    const int ncol = n0 + b_n;

    const float* abase = x + (size_t)(m0 + a_r0) * K_TOT + a_oct * 8;

    float4v acc[4][4] = {};

    for (int g = 0; g < GROUPS; ++g) {
        // ---- per-group dequant constants for this thread's column
        const float s_f = sc[g * N_TOT + ncol];
        const _Float16 s_h = (_Float16)s_f;       // exact: s_f came from fp16
        half2v s2; s2[0] = s_h; s2[1] = s_h;
        const unsigned zraw = qz[g * (N_TOT / 8) + (ncol >> 3)];
        const unsigned z = (zraw >> ((ncol & 7) * 4)) & 15u;
        const unsigned zbits = 0x64006400u | z | (z << 16);
        const half2v zb2 = __builtin_bit_cast(half2v, zbits);  // {1024+z, 1024+z}

        #pragma unroll
        for (int kt = 0; kt < 2; ++kt) {
            const int k0 = g * 128 + kt * 64;
            __syncthreads();  // protect LDS from previous iteration's reads

            // ---- stage A: permuted octets, fp32 -> fp16 RTE
            {
                const float* src = abase + k0;
                #pragma unroll
                for (int i = 0; i < 4; ++i) {
                    float4v v0 = *(const float4v*)(src + (size_t)(32 * i) * K_TOT);
                    float4v v1 = *(const float4v*)(src + (size_t)(32 * i) * K_TOT + 4);
                    half8 h;  // physical order = logical k [0,4,1,5,2,6,3,7]
                    h[0] = (_Float16)v0[0]; h[1] = (_Float16)v1[0];
                    h[2] = (_Float16)v0[1]; h[3] = (_Float16)v1[1];
                    h[4] = (_Float16)v0[2]; h[5] = (_Float16)v1[2];
                    h[6] = (_Float16)v0[3]; h[7] = (_Float16)v1[3];
                    *(half8*)&As[(a_r0 + 32 * i) * LDK + a_oct * 8] = h;
                }
            }

            // ---- stage B: packed magic-number dequant -> Bs[n][k]
            {
                const int krow0 = k0 >> 3;
                #pragma unroll
                for (int i = 0; i < 4; ++i) {
                    const int rr = b_rr + 2 * i;  // 0..7
                    const unsigned raw = qw[(size_t)(krow0 + rr) * N_TOT + ncol];
                    half2v d0 = __builtin_bit_cast(half2v, (raw         & 0x000F000Fu) | 0x64006400u);
                    half2v d1 = __builtin_bit_cast(half2v, ((raw >> 4)  & 0x000F000Fu) | 0x64006400u);
                    half2v d2 = __builtin_bit_cast(half2v, ((raw >> 8)  & 0x000F000Fu) | 0x64006400u);
                    half2v d3 = __builtin_bit_cast(half2v, ((raw >> 12) & 0x000F000Fu) | 0x64006400u);
                    d0 = (d0 - zb2) * s2;   // v_pk_sub_f16 (exact) + v_pk_mul_f16 (RTE)
                    d1 = (d1 - zb2) * s2;
                    d2 = (d2 - zb2) * s2;
                    d3 = (d3 - zb2) * s2;
                    half8 w;  // physical order = logical k [0,4,1,5,2,6,3,7]
                    w[0] = d0[0]; w[1] = d0[1];
                    w[2] = d1[0]; w[3] = d1[1];
                    w[4] = d2[0]; w[5] = d2[1];
                    w[6] = d3[0]; w[7] = d3[1];
                    *(half8*)&Bs[b_n * LDK + rr * 8] = w;  // ds_write_b128
                }
            }

            __syncthreads();

            // ---- compute: 2 x (4 A-frags + 4 B-frags + 16 MFMA)
            #pragma unroll
            for (int kk = 0; kk < 2; ++kk) {
                half8 af[4], bf[4];
                #pragma unroll
                for (int i = 0; i < 4; ++i)
                    af[i] = *(const half8*)&As[(wr * 64 + i * 16 + l16) * LDK + kk * 32 + quad * 8];
                #pragma unroll
                for (int j = 0; j < 4; ++j)
                    bf[j] = *(const half8*)&Bs[(wc * 64 + j * 16 + l16) * LDK + kk * 32 + quad * 8];
                #pragma unroll
                for (int i = 0; i < 4; ++i)
                    #pragma unroll
                    for (int j = 0; j < 4; ++j)
                        acc[i][j] = __builtin_amdgcn_mfma_f32_16x16x32_f16(af[i], bf[j], acc[i][j], 0, 0, 0);
            }
        }
    }

    // ---- epilogue: C/D layout col = lane&15 (n), row = quad*4 + reg (m)
    float* o = out + (size_t)(m0 + wr * 64) * N_TOT + (n0 + wc * 64);
    #pragma unroll
    for (int i = 0; i < 4; ++i)
        #pragma unroll
        for (int j = 0; j < 4; ++j)
            #pragma unroll
            for (int r = 0; r < 4; ++r)
                o[(size_t)(i * 16 + quad * 4 + r) * N_TOT + (j * 16 + l16)] = acc[i][j][r];
}

extern "C" void kernel_launch(void* const* d_in, const int* in_sizes, int n_in,
                              void* d_out, int out_size, void* d_ws, size_t ws_size,
                              hipStream_t stream) {
    const float* x = (const float*)d_in[0];
    const unsigned* qw = (const unsigned*)d_in[1];
    const unsigned* qz = (const unsigned*)d_in[2];
    const float* sc = (const float*)d_in[3];
    float* out = (float*)d_out;

    dim3 grid(N_TOT / BN, M_TOT / BM, 1);  // (86, 64)
    gptq_fused_gemm<<<grid, dim3(256, 1, 1), 0, stream>>>(x, qw, qz, sc, out);
}